// Round 5
// baseline (240.011 us; speedup 1.0000x reference)
//
#include <hip/hip_runtime.h>
#include <hip/hip_bf16.h>
#include <hip/hip_cooperative_groups.h>

#define NTOK 16384
#define NB 16
#define NC 256
#define NK 64
#define EPSF 1e-9f

typedef __attribute__((ext_vector_type(8))) short bf16x8;   // 8 bf16 (4 VGPRs)
typedef __attribute__((ext_vector_type(4))) float f32x4;    // MFMA C/D

__device__ inline unsigned short f2b(float f) {  // RNE f32 -> bf16 bits via HW cvt
  __hip_bfloat16 h = __float2bfloat16(f);
  return *(unsigned short*)&h;
}
__device__ inline float b2f(unsigned short u) {
  union { unsigned u; float f; } v; v.u = ((unsigned)u) << 16; return v.f;
}

// ---------------- Kernel A: weight fusion + Srow zero (baseline, unchanged) ----------------
__global__ __launch_bounds__(256) void kA(const float* __restrict__ conv1_w,
                                          const float* __restrict__ conv1_b,
                                          const float* __restrict__ w0,
                                          const float* __restrict__ w1,
                                          const float* __restrict__ b2,
                                          unsigned short* __restrict__ WeffB,
                                          unsigned short* __restrict__ w1Bb,
                                          float* __restrict__ beff,
                                          float* __restrict__ cb,
                                          float* __restrict__ Srow) {
  int blk = blockIdx.x;
  int tid = threadIdx.x;
  if (blk < NK) {
    int k = blk;
    float acc = 0.f;
#pragma unroll 8
    for (int d = 0; d < NC; ++d)
      acc = fmaf(w0[k * NC + d], conv1_w[d * NC + tid], acc);
    WeffB[k * NC + tid] = f2b(acc);
    if (tid == 0) {
      float s = 0.f;
#pragma unroll 8
      for (int d = 0; d < NC; ++d) s = fmaf(w0[k * NC + d], conv1_b[d], s);
      beff[k] = s;
    }
  } else {
    int c = tid;
    float s = 0.f;
#pragma unroll 8
    for (int k = 0; k < NK; ++k) {
      float v = w1[c * NK + k];
      s += v;
      w1Bb[c * NK + k] = f2b(v);
    }
    cb[c] = b2[0] * s;
    for (int i = tid; i < NB * NK; i += 256) Srow[i] = 0.f;
  }
}

// ---------------- Fused kernel: kB + grid barrier + kCD, ez never leaves LDS ----------------
// 512 cooperative blocks; 65.25 KB LDS/block -> LDS-capped at exactly 2 blocks/CU
// (VGPR need for 2/CU is <=256, trivially met) so the cooperative occupancy
// check passes with margin.  Block (b = bid>>5, sp = bid&31) owns slabs
// sl = sp*2+{0,1}: tokens sl*256..+255 each, both ez slabs kept in LDS.
__global__ __launch_bounds__(256, 2) void kF(const float* __restrict__ x,
                                             const unsigned short* __restrict__ WeffB,
                                             const float* __restrict__ beff,
                                             const unsigned short* __restrict__ w1Bb,
                                             const float* __restrict__ cb,
                                             const float* __restrict__ w2,
                                             float* __restrict__ Srow,
                                             float* __restrict__ out) {
  const int bid = blockIdx.x;
  const int b = bid >> 5, sp = bid & 31;
  const int tid = threadIdx.x;
  const int lane = tid & 63, w = tid >> 6, l15 = lane & 15, g = lane >> 4;

  __shared__ unsigned short slab[2][NK * 256];   // 2 x 32 KB swizzled: [k][nu]
  __shared__ float sred[4][NK];
  __shared__ float invS[NK];

  // ================= phase B: ez = exp(Weff*x + beff) into slabs + row sums ==
  const float* xb = x + (((size_t)b * NC) << 14);
  float rsum[16];
#pragma unroll
  for (int i = 0; i < 16; ++i) rsum[i] = 0.f;

#pragma unroll 1
  for (int ns = 0; ns < 2; ++ns) {
    const int sl = sp * 2 + ns;
    unsigned short* slb = slab[ns];
#pragma unroll 1
    for (int np = 0; np < 2; ++np) {
      const int n0 = sl * 256 + np * 128 + w * 32;   // token in batch
      const int nu0 = np * 128 + w * 32;             // token in slab

      f32x4 acc[4][2];
#pragma unroll
      for (int kf = 0; kf < 4; ++kf)
#pragma unroll
        for (int nf = 0; nf < 2; ++nf)
          acc[kf][nf] = (f32x4){0.f, 0.f, 0.f, 0.f};

#pragma unroll
      for (int s = 0; s < 8; ++s) {
        const int c0 = s * 32;
        bf16x8 a[4];
#pragma unroll
        for (int kf = 0; kf < 4; ++kf)
          a[kf] = *(const bf16x8*)(WeffB + ((kf * 16 + l15) << 8) + c0 + g * 8);

        bf16x8 b0, b1;
#pragma unroll
        for (int e = 0; e < 8; ++e) {
          const float2 p = *(const float2*)(xb + (((size_t)(c0 + g * 8 + e)) << 14) + n0 + 2 * l15);
          b0[e] = (short)f2b(p.x);
          b1[e] = (short)f2b(p.y);
        }

#pragma unroll
        for (int kf = 0; kf < 4; ++kf) {
          acc[kf][0] = __builtin_amdgcn_mfma_f32_16x16x32_bf16(a[kf], b0, acc[kf][0], 0, 0, 0);
          acc[kf][1] = __builtin_amdgcn_mfma_f32_16x16x32_bf16(a[kf], b1, acc[kf][1], 0, 0, 0);
        }
      }

      // epilogue: exp, pack pair, swizzled LDS store, rowsum accumulate
      const int nu = nu0 + 2 * l15;
      const int xb2 = (nu >> 6) & 3;
#pragma unroll
      for (int kf = 0; kf < 4; ++kf) {
#pragma unroll
        for (int j = 0; j < 4; ++j) {
          const int k = kf * 16 + g * 4 + j;
          const float bv = beff[k];
          float e0 = __expf(acc[kf][0][j] + bv);
          float e1 = __expf(acc[kf][1][j] + bv);
          unsigned pk = (unsigned)f2b(e0) | ((unsigned)f2b(e1) << 16);
          int o = (nu * 2) ^ ((((k & 1) << 2) | xb2) << 4);
          *(unsigned*)((char*)slb + k * 512 + o) = pk;
          rsum[kf * 4 + j] += e0 + e1;
        }
      }
    }
  }

#pragma unroll
  for (int m = 1; m < 16; m <<= 1) {
#pragma unroll
    for (int i = 0; i < 16; ++i)
      rsum[i] += __shfl_xor(rsum[i], m, 64);
  }
  if (l15 == 0) {
#pragma unroll
    for (int i = 0; i < 16; ++i)
      sred[w][(i >> 2) * 16 + g * 4 + (i & 3)] = rsum[i];
  }
  __syncthreads();
  if (tid < NK)
    atomicAdd(&Srow[b * NK + tid],
              sred[0][tid] + sred[1][tid] + sred[2][tid] + sred[3][tid]);

  // ================= grid-wide barrier: Srow complete ========================
  cooperative_groups::this_grid().sync();

  // ================= phase C: baseline kCD minus staging, per slab ===========
  if (tid < NK)
    invS[tid] = 1.f / __hip_atomic_load(&Srow[b * NK + tid],
                                        __ATOMIC_RELAXED, __HIP_MEMORY_SCOPE_AGENT);
  __syncthreads();

#pragma unroll 1
  for (int ns = 0; ns < 2; ++ns) {
    const int sl = sp * 2 + ns;
    unsigned short* slb = slab[ns];

    // per-token colsum -> sc; rewrite slab in place as q (bf16); column-private
    {
      const int nu = tid;                 // 0..255
      const int xb2 = (nu >> 6) & 3;      // bits 8:7 of nu*2
      float s = 0.f;
#pragma unroll
      for (int k = 0; k < NK; ++k) {
        int o = (nu * 2) ^ ((((k & 1) << 2) | xb2) << 4);
        s += b2f(*(const unsigned short*)((const char*)slb + k * 512 + o)) * invS[k];
      }
      const float scv = w2[0] / (EPSF + s);
#pragma unroll
      for (int k = 0; k < NK; ++k) {
        int o = (nu * 2) ^ ((((k & 1) << 2) | xb2) << 4);
        unsigned short* p = (unsigned short*)((char*)slb + k * 512 + o);
        *p = f2b(b2f(*p) * invS[k] * scv);
      }
    }
    __syncthreads();

    // GEMM out of LDS, looped over the 4 c-tiles (slab reused).
#pragma unroll 1
    for (int ct = 0; ct < 4; ++ct) {
      const int c0 = ct * 64;
      bf16x8 bfr[4][2];
#pragma unroll
      for (int cc = 0; cc < 4; ++cc)
#pragma unroll
        for (int kh = 0; kh < 2; ++kh)
          bfr[cc][kh] = *(const bf16x8*)(w1Bb + (c0 + cc * 16 + l15) * NK + kh * 32 + g * 8);

      f32x4 acc[4][4];
#pragma unroll
      for (int mi = 0; mi < 4; ++mi)
#pragma unroll
        for (int cc = 0; cc < 4; ++cc)
          acc[mi][cc] = (f32x4){0.f, 0.f, 0.f, 0.f};

#pragma unroll
      for (int mi = 0; mi < 4; ++mi) {
        const int row = w * 64 + mi * 16 + l15;
        const int ko = row >> 2, t = row & 3;
        const int swz = ((ko & 1) << 2) | t;
        const int off0 = (t * 128 + g * 16) ^ (swz << 4);
        const int off1 = (t * 128 + 64 + g * 16) ^ (swz << 4);
        bf16x8 a0 = *(const bf16x8*)((const char*)slb + ko * 512 + off0);
        bf16x8 a1 = *(const bf16x8*)((const char*)slb + ko * 512 + off1);
#pragma unroll
        for (int cc = 0; cc < 4; ++cc) {
          acc[mi][cc] = __builtin_amdgcn_mfma_f32_16x16x32_bf16(a0, bfr[cc][0], acc[mi][cc], 0, 0, 0);
          acc[mi][cc] = __builtin_amdgcn_mfma_f32_16x16x32_bf16(a1, bfr[cc][1], acc[mi][cc], 0, 0, 0);
        }
      }

      // epilogue: out[b, ko*256 + sl*4 + t, c] = acc + cb[c]
#pragma unroll
      for (int mi = 0; mi < 4; ++mi) {
#pragma unroll
        for (int j = 0; j < 4; ++j) {
          const int row = w * 64 + mi * 16 + g * 4 + j;
          const int ko = row >> 2, t = row & 3;
          float* op = out + ((size_t)b * NTOK + (size_t)ko * 256 + sl * 4 + t) * NC;
#pragma unroll
          for (int cc = 0; cc < 4; ++cc) {
            const int c = c0 + cc * 16 + l15;
            op[c] = acc[mi][cc][j] + cb[c];
          }
        }
      }
    }
    __syncthreads();
  }
}

// ---------------- Fallback kernels: round-3 proven kB + kCD (verbatim) ----------------
__global__ __launch_bounds__(256) void kB(const float* __restrict__ x,
                                          const unsigned short* __restrict__ WeffB,
                                          const float* __restrict__ beff,
                                          unsigned short* __restrict__ ezg,
                                          float* __restrict__ Srow) {
  const int b = blockIdx.y;
  const int tid = threadIdx.x;
  const int lane = tid & 63;
  const int w = tid >> 6;
  const int l15 = lane & 15;
  const int g = lane >> 4;
  const int n0 = blockIdx.x * 128 + w * 32;

  const float* xb = x + (((size_t)b * NC) << 14);

  f32x4 acc[4][2];
#pragma unroll
  for (int kf = 0; kf < 4; ++kf)
#pragma unroll
    for (int nf = 0; nf < 2; ++nf)
      acc[kf][nf] = (f32x4){0.f, 0.f, 0.f, 0.f};

#pragma unroll
  for (int s = 0; s < 8; ++s) {
    const int c0 = s * 32;
    bf16x8 a[4];
#pragma unroll
    for (int kf = 0; kf < 4; ++kf)
      a[kf] = *(const bf16x8*)(WeffB + ((kf * 16 + l15) << 8) + c0 + g * 8);

    bf16x8 b0, b1;
#pragma unroll
    for (int e = 0; e < 8; ++e) {
      const float2 p = *(const float2*)(xb + (((size_t)(c0 + g * 8 + e)) << 14) + n0 + 2 * l15);
      b0[e] = (short)f2b(p.x);
      b1[e] = (short)f2b(p.y);
    }

#pragma unroll
    for (int kf = 0; kf < 4; ++kf) {
      acc[kf][0] = __builtin_amdgcn_mfma_f32_16x16x32_bf16(a[kf], b0, acc[kf][0], 0, 0, 0);
      acc[kf][1] = __builtin_amdgcn_mfma_f32_16x16x32_bf16(a[kf], b1, acc[kf][1], 0, 0, 0);
    }
  }

  __shared__ float sred[4][NK];
  float rs[16];
#pragma unroll
  for (int kf = 0; kf < 4; ++kf) {
#pragma unroll
    for (int j = 0; j < 4; ++j) {
      const int k = kf * 16 + g * 4 + j;
      const float bv = beff[k];
      float e0 = __expf(acc[kf][0][j] + bv);
      float e1 = __expf(acc[kf][1][j] + bv);
      unsigned pk = (unsigned)f2b(e0) | ((unsigned)f2b(e1) << 16);
      *(unsigned*)(ezg + (((size_t)(b * NK + k)) << 14) + n0 + 2 * l15) = pk;
      rs[kf * 4 + j] = e0 + e1;
    }
  }
#pragma unroll
  for (int m = 1; m < 16; m <<= 1) {
#pragma unroll
    for (int i = 0; i < 16; ++i)
      rs[i] += __shfl_xor(rs[i], m, 64);
  }
  if (l15 == 0) {
#pragma unroll
    for (int i = 0; i < 16; ++i)
      sred[w][(i >> 2) * 16 + g * 4 + (i & 3)] = rs[i];
  }
  __syncthreads();
  if (tid < NK)
    atomicAdd(&Srow[b * NK + tid],
              sred[0][tid] + sred[1][tid] + sred[2][tid] + sred[3][tid]);
}

__global__ __launch_bounds__(256) void kCD(const unsigned short* __restrict__ ezg,
                                           const float* __restrict__ Srow,
                                           const unsigned short* __restrict__ w1Bb,
                                           const float* __restrict__ cb,
                                           const float* __restrict__ w2,
                                           float* __restrict__ out) {
  const int sl = blockIdx.x;
  const int b  = blockIdx.y;
  const int tid = threadIdx.x;
  const int lane = tid & 63, wv = tid >> 6, l15 = lane & 15, g = lane >> 4;

  __shared__ unsigned short slab[NK * 256];
  __shared__ float invS[NK];

  if (tid < NK) invS[tid] = 1.f / Srow[b * NK + tid];

  const size_t ebase = ((size_t)b * NK) << 14;
#pragma unroll
  for (int p = 0; p < 8; ++p) {
    int idx = p * 256 + tid;
    int k = idx >> 5, ch = idx & 31;
    float4 v = *(const float4*)(ezg + ebase + (((size_t)k) << 14) + sl * 256 + ch * 8);
    int off = (ch * 16) ^ ((((k & 1) << 2) | (ch >> 3)) << 4);
    *(float4*)((char*)slab + k * 512 + off) = v;
  }
  __syncthreads();

  {
    const int nu = tid;
    const int xb2 = (nu >> 6) & 3;
    float s = 0.f;
#pragma unroll
    for (int k = 0; k < NK; ++k) {
      int o = (nu * 2) ^ ((((k & 1) << 2) | xb2) << 4);
      s += b2f(*(const unsigned short*)((const char*)slab + k * 512 + o)) * invS[k];
    }
    const float scv = w2[0] / (EPSF + s);
#pragma unroll
    for (int k = 0; k < NK; ++k) {
      int o = (nu * 2) ^ ((((k & 1) << 2) | xb2) << 4);
      unsigned short* p = (unsigned short*)((char*)slab + k * 512 + o);
      *p = f2b(b2f(*p) * invS[k] * scv);
    }
  }
  __syncthreads();

#pragma unroll 1
  for (int ct = 0; ct < 4; ++ct) {
    const int c0 = ct * 64;
    bf16x8 bfr[4][2];
#pragma unroll
    for (int cc = 0; cc < 4; ++cc)
#pragma unroll
      for (int kh = 0; kh < 2; ++kh)
        bfr[cc][kh] = *(const bf16x8*)(w1Bb + (c0 + cc * 16 + l15) * NK + kh * 32 + g * 8);

    f32x4 acc[4][4];
#pragma unroll
    for (int mi = 0; mi < 4; ++mi)
#pragma unroll
      for (int cc = 0; cc < 4; ++cc)
        acc[mi][cc] = (f32x4){0.f, 0.f, 0.f, 0.f};

#pragma unroll
    for (int mi = 0; mi < 4; ++mi) {
      const int row = wv * 64 + mi * 16 + l15;
      const int ko = row >> 2, t = row & 3;
      const int swz = ((ko & 1) << 2) | t;
      const int off0 = (t * 128 + g * 16) ^ (swz << 4);
      const int off1 = (t * 128 + 64 + g * 16) ^ (swz << 4);
      bf16x8 a0 = *(const bf16x8*)((const char*)slab + ko * 512 + off0);
      bf16x8 a1 = *(const bf16x8*)((const char*)slab + ko * 512 + off1);
#pragma unroll
      for (int cc = 0; cc < 4; ++cc) {
        acc[mi][cc] = __builtin_amdgcn_mfma_f32_16x16x32_bf16(a0, bfr[cc][0], acc[mi][cc], 0, 0, 0);
        acc[mi][cc] = __builtin_amdgcn_mfma_f32_16x16x32_bf16(a1, bfr[cc][1], acc[mi][cc], 0, 0, 0);
      }
    }

#pragma unroll
    for (int mi = 0; mi < 4; ++mi) {
#pragma unroll
      for (int j = 0; j < 4; ++j) {
        const int row = wv * 64 + mi * 16 + g * 4 + j;
        const int ko = row >> 2, t = row & 3;
        float* op = out + ((size_t)b * NTOK + (size_t)ko * 256 + sl * 4 + t) * NC;
#pragma unroll
        for (int cc = 0; cc < 4; ++cc) {
          const int c = c0 + cc * 16 + l15;
          op[c] = acc[mi][cc][j] + cb[c];
        }
      }
    }
  }
}

extern "C" void kernel_launch(void* const* d_in, const int* in_sizes, int n_in,
                              void* d_out, int out_size, void* d_ws, size_t ws_size,
                              hipStream_t stream) {
  const float* x       = (const float*)d_in[0];
  const float* conv1_w = (const float*)d_in[1];
  const float* conv1_b = (const float*)d_in[2];
  const float* w0      = (const float*)d_in[3];
  const float* w2      = (const float*)d_in[4];
  const float* b2      = (const float*)d_in[5];
  const float* w1      = (const float*)d_in[6];
  float* out = (float*)d_out;

  unsigned short* ezg = (unsigned short*)d_ws;                 // 16*64*16384 bf16 (fallback path)
  float* beff = (float*)(ezg + (size_t)NB * NK * NTOK);        // 64
  float* cb   = beff + NK;                                     // 256
  float* Srow = cb + NC;                                       // 1024
  unsigned short* WeffB = (unsigned short*)(Srow + NB * NK);   // 64*256 bf16
  unsigned short* w1Bb  = WeffB + NK * NC;                     // 256*64 bf16

  hipLaunchKernelGGL(kA, dim3(65), dim3(256), 0, stream,
                     conv1_w, conv1_b, w0, w1, b2, WeffB, w1Bb, beff, cb, Srow);

  const unsigned short* WeffBc = WeffB;
  const unsigned short* w1Bbc  = w1Bb;
  const float* beffc = beff;
  const float* cbc   = cb;
  void* args[] = {(void*)&x, (void*)&WeffBc, (void*)&beffc, (void*)&w1Bbc,
                  (void*)&cbc, (void*)&w2, (void*)&Srow, (void*)&out};
  hipError_t cerr = hipLaunchCooperativeKernel((const void*)kF, dim3(512), dim3(256),
                                               args, 0, stream);
  if (cerr != hipSuccess) {
    // proven round-3 two-kernel path
    hipLaunchKernelGGL(kB, dim3(128, NB), dim3(256), 0, stream, x, WeffB, beff, ezg, Srow);
    hipLaunchKernelGGL(kCD, dim3(64, NB), dim3(256), 0, stream, ezg, Srow, w1Bb, cb, w2, out);
  }
}

// Round 6
// 167.781 us; speedup vs baseline: 1.4305x; 1.4305x over previous
//
#include <hip/hip_runtime.h>
#include <hip/hip_bf16.h>

#define NTOK 16384
#define NB 16
#define NC 256
#define NK 64
#define EPSF 1e-9f

typedef __attribute__((ext_vector_type(8))) short bf16x8;   // 8 bf16 (4 VGPRs)
typedef __attribute__((ext_vector_type(4))) float f32x4;    // MFMA C/D

__device__ inline unsigned short f2b(float f) {  // RNE f32 -> bf16 bits via HW cvt
  __hip_bfloat16 h = __float2bfloat16(f);
  return *(unsigned short*)&h;
}
__device__ inline float b2f(unsigned short u) {
  union { unsigned u; float f; } v; v.u = ((unsigned)u) << 16; return v.f;
}

// ---------------- Kernel A: weight fusion + Srow zero (baseline, unchanged) ----------------
__global__ __launch_bounds__(256) void kA(const float* __restrict__ conv1_w,
                                          const float* __restrict__ conv1_b,
                                          const float* __restrict__ w0,
                                          const float* __restrict__ w1,
                                          const float* __restrict__ b2,
                                          unsigned short* __restrict__ WeffB,
                                          unsigned short* __restrict__ w1Bb,
                                          float* __restrict__ beff,
                                          float* __restrict__ cb,
                                          float* __restrict__ Srow) {
  int blk = blockIdx.x;
  int tid = threadIdx.x;
  if (blk < NK) {
    int k = blk;
    float acc = 0.f;
#pragma unroll 8
    for (int d = 0; d < NC; ++d)
      acc = fmaf(w0[k * NC + d], conv1_w[d * NC + tid], acc);
    WeffB[k * NC + tid] = f2b(acc);
    if (tid == 0) {
      float s = 0.f;
#pragma unroll 8
      for (int d = 0; d < NC; ++d) s = fmaf(w0[k * NC + d], conv1_b[d], s);
      beff[k] = s;
    }
  } else {
    int c = tid;
    float s = 0.f;
#pragma unroll 8
    for (int k = 0; k < NK; ++k) {
      float v = w1[c * NK + k];
      s += v;
      w1Bb[c * NK + k] = f2b(v);
    }
    cb[c] = b2[0] * s;
    for (int i = tid; i < NB * NK; i += 256) Srow[i] = 0.f;
  }
}

// ---------------- Kernel B: ez = exp(Weff*x + beff) + row sums ----------------
// ONLY change vs round-3: explicit double-buffered register prefetch of the
// x float2 loads — s+1's 8 loads issue before s's MFMAs consume s's data, so
// >=16 loads stay in flight per wave across the unrolled loop. Arithmetic,
// values, and the ezg store pattern are bitwise identical to round-3.
__global__ __launch_bounds__(256) void kB(const float* __restrict__ x,
                                          const unsigned short* __restrict__ WeffB,
                                          const float* __restrict__ beff,
                                          unsigned short* __restrict__ ezg,
                                          float* __restrict__ Srow) {
  const int b = blockIdx.y;
  const int tid = threadIdx.x;
  const int lane = tid & 63;
  const int w = tid >> 6;
  const int l15 = lane & 15;
  const int g = lane >> 4;
  const int n0 = blockIdx.x * 128 + w * 32;

  const float* xb = x + (((size_t)b * NC) << 14) + n0 + 2 * l15;

  f32x4 acc[4][2];
#pragma unroll
  for (int kf = 0; kf < 4; ++kf)
#pragma unroll
    for (int nf = 0; nf < 2; ++nf)
      acc[kf][nf] = (f32x4){0.f, 0.f, 0.f, 0.f};

  // prime: s=0's x loads
  float2 xp[8];
#pragma unroll
  for (int e = 0; e < 8; ++e)
    xp[e] = *(const float2*)(xb + (((size_t)(g * 8 + e)) << 14));

#pragma unroll
  for (int s = 0; s < 8; ++s) {
    const int c0 = s * 32;
    bf16x8 a[4];
#pragma unroll
    for (int kf = 0; kf < 4; ++kf)
      a[kf] = *(const bf16x8*)(WeffB + ((kf * 16 + l15) << 8) + c0 + g * 8);

    // prefetch next s-iter's x before consuming this one
    float2 xn[8];
    if (s < 7) {
#pragma unroll
      for (int e = 0; e < 8; ++e)
        xn[e] = *(const float2*)(xb + (((size_t)(c0 + 32 + g * 8 + e)) << 14));
    }

    bf16x8 b0, b1;
#pragma unroll
    for (int e = 0; e < 8; ++e) {
      b0[e] = (short)f2b(xp[e].x);
      b1[e] = (short)f2b(xp[e].y);
    }

#pragma unroll
    for (int kf = 0; kf < 4; ++kf) {
      acc[kf][0] = __builtin_amdgcn_mfma_f32_16x16x32_bf16(a[kf], b0, acc[kf][0], 0, 0, 0);
      acc[kf][1] = __builtin_amdgcn_mfma_f32_16x16x32_bf16(a[kf], b1, acc[kf][1], 0, 0, 0);
    }

    if (s < 7) {
#pragma unroll
      for (int e = 0; e < 8; ++e) xp[e] = xn[e];
    }
  }

  __shared__ float sred[4][NK];
  float rs[16];
#pragma unroll
  for (int kf = 0; kf < 4; ++kf) {
#pragma unroll
    for (int j = 0; j < 4; ++j) {
      const int k = kf * 16 + g * 4 + j;
      const float bv = beff[k];
      float e0 = __expf(acc[kf][0][j] + bv);
      float e1 = __expf(acc[kf][1][j] + bv);
      unsigned pk = (unsigned)f2b(e0) | ((unsigned)f2b(e1) << 16);
      *(unsigned*)(ezg + (((size_t)(b * NK + k)) << 14) + n0 + 2 * l15) = pk;
      rs[kf * 4 + j] = e0 + e1;
    }
  }
#pragma unroll
  for (int m = 1; m < 16; m <<= 1) {
#pragma unroll
    for (int i = 0; i < 16; ++i)
      rs[i] += __shfl_xor(rs[i], m, 64);
  }
  if (l15 == 0) {
#pragma unroll
    for (int i = 0; i < 16; ++i)
      sred[w][(i >> 2) * 16 + g * 4 + (i & 3)] = rs[i];
  }
  __syncthreads();
  if (tid < NK)
    atomicAdd(&Srow[b * NK + tid],
              sred[0][tid] + sred[1][tid] + sred[2][tid] + sred[3][tid]);
}

// ---------------- Kernel CD: round-3 proven version (byte-identical) ----------------
__global__ __launch_bounds__(256) void kCD(const unsigned short* __restrict__ ezg,
                                           const float* __restrict__ Srow,
                                           const unsigned short* __restrict__ w1Bb,
                                           const float* __restrict__ cb,
                                           const float* __restrict__ w2,
                                           float* __restrict__ out) {
  const int sl = blockIdx.x;      // nu0 = sl*256
  const int b  = blockIdx.y;
  const int tid = threadIdx.x;
  const int lane = tid & 63, wv = tid >> 6, l15 = lane & 15, g = lane >> 4;

  __shared__ unsigned short slab[NK * 256];   // 32 KB swizzled: [ko][nu'=t*64+k]
  __shared__ float invS[NK];

  if (tid < NK) invS[tid] = 1.f / Srow[b * NK + tid];

  // phase 1: stage slab (coalesced global read, swizzled LDS write)
  const size_t ebase = ((size_t)b * NK) << 14;
#pragma unroll
  for (int p = 0; p < 8; ++p) {
    int idx = p * 256 + tid;
    int k = idx >> 5, ch = idx & 31;
    float4 v = *(const float4*)(ezg + ebase + (((size_t)k) << 14) + sl * 256 + ch * 8);
    int off = (ch * 16) ^ ((((k & 1) << 2) | (ch >> 3)) << 4);
    *(float4*)((char*)slab + k * 512 + off) = v;
  }
  __syncthreads();

  // phase 2: per-token colsum -> sc; rewrite slab in place as q (bf16)
  {
    const int nu = tid;                 // 0..255
    const int xb2 = (nu >> 6) & 3;      // bits 8:7 of nu*2
    float s = 0.f;
#pragma unroll
    for (int k = 0; k < NK; ++k) {
      int o = (nu * 2) ^ ((((k & 1) << 2) | xb2) << 4);
      s += b2f(*(const unsigned short*)((const char*)slab + k * 512 + o)) * invS[k];
    }
    const float scv = w2[0] / (EPSF + s);
#pragma unroll
    for (int k = 0; k < NK; ++k) {
      int o = (nu * 2) ^ ((((k & 1) << 2) | xb2) << 4);
      unsigned short* p = (unsigned short*)((char*)slab + k * 512 + o);
      *p = f2b(b2f(*p) * invS[k] * scv);
    }
  }
  __syncthreads();

  // phase 3: GEMM out of LDS, looped over the 4 c-tiles (slab reused).
#pragma unroll 1
  for (int ct = 0; ct < 4; ++ct) {
    const int c0 = ct * 64;
    bf16x8 bfr[4][2];
#pragma unroll
    for (int cc = 0; cc < 4; ++cc)
#pragma unroll
      for (int kh = 0; kh < 2; ++kh)
        bfr[cc][kh] = *(const bf16x8*)(w1Bb + (c0 + cc * 16 + l15) * NK + kh * 32 + g * 8);

    f32x4 acc[4][4];
#pragma unroll
    for (int mi = 0; mi < 4; ++mi)
#pragma unroll
      for (int cc = 0; cc < 4; ++cc)
        acc[mi][cc] = (f32x4){0.f, 0.f, 0.f, 0.f};

#pragma unroll
    for (int mi = 0; mi < 4; ++mi) {
      const int row = wv * 64 + mi * 16 + l15;
      const int ko = row >> 2, t = row & 3;
      const int swz = ((ko & 1) << 2) | t;
      const int off0 = (t * 128 + g * 16) ^ (swz << 4);
      const int off1 = (t * 128 + 64 + g * 16) ^ (swz << 4);
      bf16x8 a0 = *(const bf16x8*)((const char*)slab + ko * 512 + off0);
      bf16x8 a1 = *(const bf16x8*)((const char*)slab + ko * 512 + off1);
#pragma unroll
      for (int cc = 0; cc < 4; ++cc) {
        acc[mi][cc] = __builtin_amdgcn_mfma_f32_16x16x32_bf16(a0, bfr[cc][0], acc[mi][cc], 0, 0, 0);
        acc[mi][cc] = __builtin_amdgcn_mfma_f32_16x16x32_bf16(a1, bfr[cc][1], acc[mi][cc], 0, 0, 0);
      }
    }

    // epilogue: out[b, ko*256 + sl*4 + t, c] = acc + cb[c]
#pragma unroll
    for (int mi = 0; mi < 4; ++mi) {
#pragma unroll
      for (int j = 0; j < 4; ++j) {
        const int row = wv * 64 + mi * 16 + g * 4 + j;
        const int ko = row >> 2, t = row & 3;
        float* op = out + ((size_t)b * NTOK + (size_t)ko * 256 + sl * 4 + t) * NC;
#pragma unroll
        for (int cc = 0; cc < 4; ++cc) {
          const int c = c0 + cc * 16 + l15;
          op[c] = acc[mi][cc][j] + cb[c];
        }
      }
    }
  }
}

extern "C" void kernel_launch(void* const* d_in, const int* in_sizes, int n_in,
                              void* d_out, int out_size, void* d_ws, size_t ws_size,
                              hipStream_t stream) {
  const float* x       = (const float*)d_in[0];
  const float* conv1_w = (const float*)d_in[1];
  const float* conv1_b = (const float*)d_in[2];
  const float* w0      = (const float*)d_in[3];
  const float* w2      = (const float*)d_in[4];
  const float* b2      = (const float*)d_in[5];
  const float* w1      = (const float*)d_in[6];
  float* out = (float*)d_out;

  unsigned short* ezg = (unsigned short*)d_ws;                 // 16*64*16384 bf16
  float* beff = (float*)(ezg + (size_t)NB * NK * NTOK);        // 64
  float* cb   = beff + NK;                                     // 256
  float* Srow = cb + NC;                                       // 1024
  unsigned short* WeffB = (unsigned short*)(Srow + NB * NK);   // 64*256 bf16
  unsigned short* w1Bb  = WeffB + NK * NC;                     // 256*64 bf16

  hipLaunchKernelGGL(kA, dim3(65), dim3(256), 0, stream,
                     conv1_w, conv1_b, w0, w1, b2, WeffB, w1Bb, beff, cb, Srow);
  hipLaunchKernelGGL(kB, dim3(128, NB), dim3(256), 0, stream, x, WeffB, beff, ezg, Srow);
  hipLaunchKernelGGL(kCD, dim3(64, NB), dim3(256), 0, stream, ezg, Srow, w1Bb, cb, w2, out);
}